// Round 4
// baseline (605.024 us; speedup 1.0000x reference)
//
#include <hip/hip_runtime.h>
#include <hip/hip_bf16.h>
#include <math.h>

#define B_ 8
#define N_ 8192
#define E_ 16384
#define D_ 128
#define R_ 200
#define M_ 20
#define L_ 3
#define KEFF 384   // comp(128) + h_src(128) + conf(128); dist/rel blocks folded into tables

typedef __attribute__((ext_vector_type(8))) short bf16x8;
typedef __attribute__((ext_vector_type(4))) float f32x4;

__device__ __forceinline__ short f2b(float f) {
  union { __hip_bfloat16 b; short s; } u;
  u.b = __float2bfloat16(f);
  return u.s;
}
__device__ __forceinline__ bf16x8 pack8(float4 x, float4 y) {
  bf16x8 r;
  r[0] = f2b(x.x); r[1] = f2b(x.y); r[2] = f2b(x.z); r[3] = f2b(x.w);
  r[4] = f2b(y.x); r[5] = f2b(y.y); r[6] = f2b(y.z); r[7] = f2b(y.w);
  return r;
}
__device__ __forceinline__ bf16x8 pack8mul(float4 x, float4 rx, float4 y, float4 ry) {
  bf16x8 r;
  r[0] = f2b(x.x * rx.x); r[1] = f2b(x.y * rx.y); r[2] = f2b(x.z * rx.z); r[3] = f2b(x.w * rx.w);
  r[4] = f2b(y.x * ry.x); r[5] = f2b(y.y * ry.y); r[6] = f2b(y.z * ry.z); r[7] = f2b(y.w * ry.w);
  return r;
}

// ---------------- h init: h = dist_table[clip(dists)] + 0.1*noise ----------------
__global__ __launch_bounds__(256) void k_init_h(const int* __restrict__ dists,
    const float* __restrict__ noise, const float* __restrict__ dist_table,
    float* __restrict__ h) {
  int i = blockIdx.x * 256 + threadIdx.x;   // float4 index, total B*N*D/4
  int row = i >> 5;                          // D/4 = 32 float4 per row
  int d4 = i & 31;
  int dc = dists[row]; dc = dc < 0 ? 0 : (dc > 9 ? 9 : dc);
  const float4 t = *(const float4*)&dist_table[dc * D_ + d4 * 4];
  const float4 nz = *(const float4*)&noise[(size_t)i * 4];
  float4 o;
  o.x = t.x + 0.1f * nz.x; o.y = t.y + 0.1f * nz.y;
  o.z = t.z + 0.1f * nz.z; o.w = t.w + 0.1f * nz.w;
  *(float4*)&h[(size_t)i * 4] = o;
}

// ---------------- active-edge compaction ----------------
__global__ __launch_bounds__(256) void k_compact(const int* __restrict__ edge_mask,
    int* __restrict__ count, int* __restrict__ list) {
  int i = blockIdx.x * 256 + threadIdx.x;
  bool act = edge_mask[i] != 0;
  unsigned long long m = __ballot(act);
  int lane = threadIdx.x & 63;
  int base = 0;
  if (lane == 0) base = atomicAdd(count, __popcll(m));
  base = __shfl(base, 0);
  if (act) list[base + __popcll(m & ((1ull << lane) - 1ull))] = i;  // i = b*E+e
}

// ------- T3b[k][t][d] = dist_table[t]@W3[k] + msg_b[k],  T4[k][r][d] = rel_table[r]@W4[k]
__global__ __launch_bounds__(128) void k_tables(const float* __restrict__ dist_table,
    const float* __restrict__ rel_table, const float* __restrict__ msg_W,
    const float* __restrict__ msg_b, float* __restrict__ T3b, float* __restrict__ T4) {
  int k = blockIdx.x / 210;
  int r = blockIdx.x % 210;
  int d = threadIdx.x;
  if (r < 10) {
    float acc = msg_b[k * D_ + d];
    for (int f = 0; f < D_; ++f)
      acc = fmaf(dist_table[r * D_ + f], msg_W[(size_t)(k * 640 + 256 + f) * D_ + d], acc);
    T3b[(k * 10 + r) * D_ + d] = acc;
  } else {
    int rr = r - 10;
    float acc = 0.f;
    for (int f = 0; f < D_; ++f)
      acc = fmaf(rel_table[rr * D_ + f], msg_W[(size_t)(k * 640 + 384 + f) * D_ + d], acc);
    T4[(k * R_ + rr) * D_ + d] = acc;
  }
}

// ------- Wbt_msg[k][n][fe] (bf16): effective msg weight, n-major so B-frags read contiguous
__global__ __launch_bounds__(256) void k_wbt_msg(const float* __restrict__ msg_W,
    short* __restrict__ Wbt) {
  int idx = blockIdx.x * 256 + threadIdx.x;   // L*128*384
  int fe = idx % KEFF;
  int t = idx / KEFF;
  int n = t & 127;
  int k = t >> 7;
  int row = fe < 256 ? fe : fe + 256;         // skip dist(256:384)/rel(384:512) blocks
  Wbt[idx] = f2b(msg_W[(size_t)(k * 640 + row) * D_ + n]);
}

__global__ __launch_bounds__(256) void k_wbt_upd(const float* __restrict__ upd_W,
    short* __restrict__ Wbt) {
  int idx = blockIdx.x * 256 + threadIdx.x;   // L*128*128, layout [k][n][f]
  int f = idx & 127;
  int t = idx >> 7;
  int n = t & 127;
  int k = t >> 7;
  Wbt[idx] = f2b(upd_W[(size_t)(k * D_ + f) * D_ + n]);
}

// ---------------- message GEMM (MFMA, no-LDS fragments) + scatter ----------------
// 64 edges x 128 out per block; 4 waves each own a 32x64 tile. A-frags built per-lane
// directly from gathered global rows (h/rel/conf); B-frags read 16B/lane from L2-hot Wbt.
// No barriers in the K-loop -> fully software-pipelined.
__global__ __launch_bounds__(256) void k_msg(
    const int* __restrict__ count_p, const int* __restrict__ list,
    const int* __restrict__ edge_index, const int* __restrict__ rels,
    const int* __restrict__ dists, const float* __restrict__ h,
    const float* __restrict__ rel_table, const float* __restrict__ conf,
    const short* __restrict__ Wbt,    // [128][384] bf16 (n-major), this layer
    const float* __restrict__ T3b,    // [10][128]
    const float* __restrict__ T4,     // [200][128]
    float* __restrict__ aggr) {
  int cnt = *count_p;
  int base = blockIdx.x * 64;
  if (base >= cnt) return;
  int ne = min(64, cnt - base);
  __shared__ int sMeta[64][5];                 // hsrc_row, id(conf row), aggr_row, dclip, rel
  int tid = threadIdx.x;
  if (tid < 64) {
    int t = tid < ne ? tid : 0;                // pad rows alias edge 0 (valid addresses)
    int id = list[base + t];
    int b = id >> 14;                          // E = 2^14
    int e = id & (E_ - 1);
    int src = edge_index[(b * 2) * E_ + e];
    int tgt = edge_index[(b * 2 + 1) * E_ + e];
    int dc = dists[b * N_ + src];
    dc = dc < 0 ? 0 : (dc > 9 ? 9 : dc);
    sMeta[tid][0] = b * N_ + src;
    sMeta[tid][1] = id;
    sMeta[tid][2] = b * N_ + tgt;
    sMeta[tid][3] = dc;
    sMeta[tid][4] = rels[id];
  }
  __syncthreads();
  int lane = tid & 63, wv = tid >> 6;
  int wm = wv >> 1, wn = wv & 1;               // wave tile: rows [wm*32,+32), cols [wn*64,+64)
  int g = lane >> 4, cl = lane & 15;
  int r0 = wm * 32 + cl, r1 = r0 + 16;         // the two A-frag rows this lane serves
  const float* ph0 = h + (size_t)sMeta[r0][0] * D_;
  const float* ph1 = h + (size_t)sMeta[r1][0] * D_;
  const float* pr0 = rel_table + (size_t)sMeta[r0][4] * D_;
  const float* pr1 = rel_table + (size_t)sMeta[r1][4] * D_;
  const float* pc0 = conf + (size_t)sMeta[r0][1] * D_;
  const float* pc1 = conf + (size_t)sMeta[r1][1] * D_;
  const short* wb = Wbt + (size_t)(wn * 64 + cl) * KEFF;   // tn adds tn*16*KEFF

  f32x4 acc[2][4];
  f32x4 zz = {0.f, 0.f, 0.f, 0.f};
#pragma unroll
  for (int tm = 0; tm < 2; ++tm)
#pragma unroll
    for (int tn = 0; tn < 4; ++tn) acc[tm][tn] = zz;

#pragma unroll
  for (int kstep = 0; kstep < 12; ++kstep) {   // 12 K-steps of 32; phase uniform per kstep
    const int phase = kstep >> 2;              // 0=comp, 1=h_src, 2=conf
    const int o = (kstep & 3) * 32 + g * 8;
    bf16x8 a0, a1;
    if (phase == 0) {
      float4 xa = *(const float4*)(ph0 + o), xb = *(const float4*)(ph0 + o + 4);
      float4 ra = *(const float4*)(pr0 + o), rb = *(const float4*)(pr0 + o + 4);
      float4 ya = *(const float4*)(ph1 + o), yb = *(const float4*)(ph1 + o + 4);
      float4 sa = *(const float4*)(pr1 + o), sb = *(const float4*)(pr1 + o + 4);
      a0 = pack8mul(xa, ra, xb, rb);
      a1 = pack8mul(ya, sa, yb, sb);
    } else if (phase == 1) {
      a0 = pack8(*(const float4*)(ph0 + o), *(const float4*)(ph0 + o + 4));
      a1 = pack8(*(const float4*)(ph1 + o), *(const float4*)(ph1 + o + 4));
    } else {
      a0 = pack8(*(const float4*)(pc0 + o), *(const float4*)(pc0 + o + 4));
      a1 = pack8(*(const float4*)(pc1 + o), *(const float4*)(pc1 + o + 4));
    }
    const short* wk = wb + kstep * 32 + g * 8;
    bf16x8 b0 = *(const bf16x8*)(wk);
    bf16x8 b1 = *(const bf16x8*)(wk + 16 * KEFF);
    bf16x8 b2 = *(const bf16x8*)(wk + 32 * KEFF);
    bf16x8 b3 = *(const bf16x8*)(wk + 48 * KEFF);
    acc[0][0] = __builtin_amdgcn_mfma_f32_16x16x32_bf16(a0, b0, acc[0][0], 0, 0, 0);
    acc[0][1] = __builtin_amdgcn_mfma_f32_16x16x32_bf16(a0, b1, acc[0][1], 0, 0, 0);
    acc[0][2] = __builtin_amdgcn_mfma_f32_16x16x32_bf16(a0, b2, acc[0][2], 0, 0, 0);
    acc[0][3] = __builtin_amdgcn_mfma_f32_16x16x32_bf16(a0, b3, acc[0][3], 0, 0, 0);
    acc[1][0] = __builtin_amdgcn_mfma_f32_16x16x32_bf16(a1, b0, acc[1][0], 0, 0, 0);
    acc[1][1] = __builtin_amdgcn_mfma_f32_16x16x32_bf16(a1, b1, acc[1][1], 0, 0, 0);
    acc[1][2] = __builtin_amdgcn_mfma_f32_16x16x32_bf16(a1, b2, acc[1][2], 0, 0, 0);
    acc[1][3] = __builtin_amdgcn_mfma_f32_16x16x32_bf16(a1, b3, acc[1][3], 0, 0, 0);
  }
  // ---- epilogue: bias + relu + atomic scatter ----
#pragma unroll
  for (int tm = 0; tm < 2; ++tm)
#pragma unroll
    for (int reg = 0; reg < 4; ++reg) {
      int edge = wm * 32 + tm * 16 + g * 4 + reg;   // C/D: row=(lane>>4)*4+reg, col=lane&15
      if (edge < ne) {
        int arow = sMeta[edge][2];
        int dc = sMeta[edge][3];
        int rl = sMeta[edge][4];
#pragma unroll
        for (int tn = 0; tn < 4; ++tn) {
          int n = wn * 64 + tn * 16 + cl;
          float bias = T3b[dc * D_ + n] + T4[rl * D_ + n];
          float vv = fmaxf(acc[tm][tn][reg] + bias, 0.f);
          unsafeAtomicAdd(&aggr[(size_t)arow * D_ + n], vv);
        }
      }
    }
}

// ---------------- node update (MFMA, no-LDS): h = aggr@upd_W + upd_b + h ; aggr = 0 ----------------
__global__ __launch_bounds__(256) void k_upd(
    float* __restrict__ aggr, const short* __restrict__ Wbt,   // [128][128] bf16 n-major
    const float* __restrict__ upd_b, float* __restrict__ h) {
  int base = blockIdx.x * 64;
  int tid = threadIdx.x;
  int lane = tid & 63, wv = tid >> 6;
  int wm = wv >> 1, wn = wv & 1;
  int g = lane >> 4, cl = lane & 15;
  const float* pa0 = aggr + (size_t)(base + wm * 32 + cl) * D_;
  const float* pa1 = pa0 + 16 * D_;
  const short* wb = Wbt + (size_t)(wn * 64 + cl) * D_;

  f32x4 acc[2][4];
  f32x4 zz = {0.f, 0.f, 0.f, 0.f};
#pragma unroll
  for (int tm = 0; tm < 2; ++tm)
#pragma unroll
    for (int tn = 0; tn < 4; ++tn) acc[tm][tn] = zz;

#pragma unroll
  for (int kstep = 0; kstep < 4; ++kstep) {
    int o = kstep * 32 + g * 8;
    bf16x8 a0 = pack8(*(const float4*)(pa0 + o), *(const float4*)(pa0 + o + 4));
    bf16x8 a1 = pack8(*(const float4*)(pa1 + o), *(const float4*)(pa1 + o + 4));
    const short* wk = wb + o;
    bf16x8 b0 = *(const bf16x8*)(wk);
    bf16x8 b1 = *(const bf16x8*)(wk + 16 * D_);
    bf16x8 b2 = *(const bf16x8*)(wk + 32 * D_);
    bf16x8 b3 = *(const bf16x8*)(wk + 48 * D_);
    acc[0][0] = __builtin_amdgcn_mfma_f32_16x16x32_bf16(a0, b0, acc[0][0], 0, 0, 0);
    acc[0][1] = __builtin_amdgcn_mfma_f32_16x16x32_bf16(a0, b1, acc[0][1], 0, 0, 0);
    acc[0][2] = __builtin_amdgcn_mfma_f32_16x16x32_bf16(a0, b2, acc[0][2], 0, 0, 0);
    acc[0][3] = __builtin_amdgcn_mfma_f32_16x16x32_bf16(a0, b3, acc[0][3], 0, 0, 0);
    acc[1][0] = __builtin_amdgcn_mfma_f32_16x16x32_bf16(a1, b0, acc[1][0], 0, 0, 0);
    acc[1][1] = __builtin_amdgcn_mfma_f32_16x16x32_bf16(a1, b1, acc[1][1], 0, 0, 0);
    acc[1][2] = __builtin_amdgcn_mfma_f32_16x16x32_bf16(a1, b2, acc[1][2], 0, 0, 0);
    acc[1][3] = __builtin_amdgcn_mfma_f32_16x16x32_bf16(a1, b3, acc[1][3], 0, 0, 0);
  }
  __syncthreads();                              // all aggr reads done (vmcnt drain at barrier)
  // cooperative re-zero of this block's aggr rows for the next layer
  float4 z4 = make_float4(0.f, 0.f, 0.f, 0.f);
  float4* az = (float4*)(aggr + (size_t)base * D_);
#pragma unroll
  for (int s = 0; s < 8; ++s) az[tid + s * 256] = z4;
  // epilogue: h += acc + b
#pragma unroll
  for (int tm = 0; tm < 2; ++tm)
#pragma unroll
    for (int reg = 0; reg < 4; ++reg) {
      int grow = base + wm * 32 + tm * 16 + g * 4 + reg;
#pragma unroll
      for (int tn = 0; tn < 4; ++tn) {
        int n = wn * 64 + tn * 16 + cl;
        size_t gi = (size_t)grow * D_ + n;
        h[gi] = acc[tm][tn][reg] + upd_b[n] + h[gi];
      }
    }
}

// ---------------- scores: one wave per node, full att_in dot ----------------
__global__ __launch_bounds__(256) void k_score(const float* __restrict__ h,
    const int* __restrict__ node_mask, const float* __restrict__ r_query,
    const float* __restrict__ att_W, const float* __restrict__ att_b,
    float* __restrict__ sSg) {
  int wv = threadIdx.x >> 6, lane = threadIdx.x & 63;
  int node = blockIdx.x * 4 + wv;              // [0, B*N)
  int b = node >> 13;                           // N = 2^13
  float s;
  if (node_mask[node] == 0) {
    s = -1e9f;
  } else {
    float2 hv = *(const float2*)&h[(size_t)node * D_ + lane * 2];
    float2 w0 = *(const float2*)&att_W[lane * 2];
    float2 w1 = *(const float2*)&att_W[D_ + lane * 2];
    float2 rq = *(const float2*)&r_query[b * D_ + lane * 2];
    float v = hv.x * w0.x + hv.y * w0.y + rq.x * w1.x + rq.y * w1.y;
#pragma unroll
    for (int off = 32; off > 0; off >>= 1) v += __shfl_xor(v, off);
    v += att_b[0];
    s = v > 0.f ? v : 0.01f * v;
  }
  if (lane == 0) sSg[node] = s;
}

// ---------------- per-batch: softmax stats + top-20 + outputs ----------------
__global__ __launch_bounds__(1024) void k_top(const float* __restrict__ sSg,
    const float* __restrict__ h, const int* __restrict__ node_mask,
    float* __restrict__ out) {
  int b = blockIdx.x;
  int tid = threadIdx.x, lane = tid & 63, wv = tid >> 6;   // 16 waves
  __shared__ float sS[N_];
  __shared__ float sRw[16];
  __shared__ float sSegV[16];
  __shared__ int sSegI[16];
  __shared__ float sTopV[M_];
  __shared__ int sTopI[M_];
  __shared__ float sMax, sSum;
  const float4* gp = (const float4*)&sSg[(size_t)b * N_];
#pragma unroll
  for (int r = 0; r < 2; ++r) {
    float4 x = gp[tid + r * 1024];
    *(float4*)&sS[(tid + r * 1024) * 4] = x;
  }
  __syncthreads();
  // block max
  float lm = -INFINITY;
  for (int n = tid; n < N_; n += 1024) lm = fmaxf(lm, sS[n]);
#pragma unroll
  for (int off = 32; off > 0; off >>= 1) lm = fmaxf(lm, __shfl_xor(lm, off));
  if (lane == 0) sRw[wv] = lm;
  __syncthreads();
  if (tid == 0) {
    float m = sRw[0];
    for (int i = 1; i < 16; ++i) m = fmaxf(m, sRw[i]);
    sMax = m;
  }
  __syncthreads();
  float mx = sMax;
  // softmax denom
  float ls = 0.f;
  for (int n = tid; n < N_; n += 1024) ls += expf(sS[n] - mx);
#pragma unroll
  for (int off = 32; off > 0; off >>= 1) ls += __shfl_xor(ls, off);
  if (lane == 0) sRw[wv] = ls;
  __syncthreads();
  if (tid == 0) {
    float s = 0.f;
    for (int i = 0; i < 16; ++i) s += sRw[i];
    sSum = s;
  }
  // per-wave segment argmax (segment = 512 nodes), ties -> lowest index
  {
    float bv = -INFINITY; int bi = 0;
    int s0 = wv * 512;
    for (int t2 = 0; t2 < 8; ++t2) {
      int n = s0 + lane + t2 * 64;
      float x = sS[n];
      if (x > bv) { bv = x; bi = n; }
    }
#pragma unroll
    for (int off = 32; off > 0; off >>= 1) {
      float vv = __shfl_xor(bv, off); int ii = __shfl_xor(bi, off);
      if (vv > bv || (vv == bv && ii < bi)) { bv = vv; bi = ii; }
    }
    if (lane == 0) { sSegV[wv] = bv; sSegI[wv] = bi; }
  }
  __syncthreads();
  // top-20: pick best segment, knock out, rescan only that segment
  for (int j = 0; j < M_; ++j) {
    if (wv == 0) {
      float bv = (lane < 16) ? sSegV[lane] : -INFINITY;
      int bi = (lane < 16) ? sSegI[lane] : 0x7fffffff;
#pragma unroll
      for (int off = 32; off > 0; off >>= 1) {
        float vv = __shfl_xor(bv, off); int ii = __shfl_xor(bi, off);
        if (vv > bv || (vv == bv && ii < bi)) { bv = vv; bi = ii; }
      }
      if (lane == 0) { sTopV[j] = bv; sTopI[j] = bi; sS[bi] = -INFINITY; }
    }
    __syncthreads();
    int seg = sTopI[j] >> 9;
    if (wv == seg) {
      float bv = -INFINITY; int bi = 0;
      int s0 = wv * 512;
      for (int t2 = 0; t2 < 8; ++t2) {
        int n = s0 + lane + t2 * 64;
        float x = sS[n];
        if (x > bv) { bv = x; bi = n; }
      }
#pragma unroll
      for (int off = 32; off > 0; off >>= 1) {
        float vv = __shfl_xor(bv, off); int ii = __shfl_xor(bi, off);
        if (vv > bv || (vv == bv && ii < bi)) { bv = vv; bi = ii; }
      }
      if (lane == 0) { sSegV[wv] = bv; sSegI[wv] = bi; }
    }
    __syncthreads();
  }
  float sum = sSum;
  // t_state = (h*mask)[b,0,:]
  if (tid < D_) {
    float vv = node_mask[b * N_] ? h[(size_t)b * N_ * D_ + tid] : 0.f;
    out[B_ * M_ * D_ + b * D_ + tid] = vv;
  }
  // H_evd[b,j,:] = (h*mask)[b,idx_j,:] * alpha_j
  for (int s2 = tid; s2 < M_ * D_; s2 += 1024) {
    int j = s2 >> 7, d = s2 & 127;
    int idx = sTopI[j];
    float alpha = expf(sTopV[j] - mx) / sum;
    float hv = h[((size_t)b * N_ + idx) * D_ + d];
    if (!node_mask[b * N_ + idx]) hv = 0.f;
    out[(b * M_ + j) * D_ + d] = hv * alpha;
  }
}

// ---------------- host ----------------
extern "C" void kernel_launch(void* const* d_in, const int* in_sizes, int n_in,
                              void* d_out, int out_size, void* d_ws, size_t ws_size,
                              hipStream_t stream) {
  const int*   dists      = (const int*)d_in[0];
  const int*   edge_index = (const int*)d_in[1];
  const int*   rels       = (const int*)d_in[2];
  const int*   node_mask  = (const int*)d_in[3];
  const int*   edge_mask  = (const int*)d_in[4];
  const float* r_query    = (const float*)d_in[5];
  const float* conf       = (const float*)d_in[6];
  const float* noise      = (const float*)d_in[7];
  const float* dist_table = (const float*)d_in[8];
  const float* rel_table  = (const float*)d_in[9];
  const float* msg_W      = (const float*)d_in[10];
  const float* msg_b      = (const float*)d_in[11];
  const float* upd_W      = (const float*)d_in[12];
  const float* upd_b      = (const float*)d_in[13];
  const float* att_W      = (const float*)d_in[14];
  const float* att_b      = (const float*)d_in[15];
  float* out = (float*)d_out;

  char* ws = (char*)d_ws;
  size_t off = 0;
  auto alloc = [&](size_t bytes) {
    void* p = ws + off;
    off = (off + bytes + 255) & ~(size_t)255;
    return p;
  };
  int*   count   = (int*)alloc(4);
  int*   list    = (int*)alloc((size_t)B_ * E_ * 4);
  float* h       = (float*)alloc((size_t)B_ * N_ * D_ * 4);
  float* aggr    = (float*)alloc((size_t)B_ * N_ * D_ * 4);
  short* Wbt_msg = (short*)alloc((size_t)L_ * D_ * KEFF * 2);
  short* Wbt_upd = (short*)alloc((size_t)L_ * D_ * D_ * 2);
  float* T3b     = (float*)alloc((size_t)L_ * 10 * D_ * 4);
  float* T4      = (float*)alloc((size_t)L_ * R_ * D_ * 4);
  float* scores  = (float*)alloc((size_t)B_ * N_ * 4);
  (void)ws_size; (void)in_sizes; (void)n_in; (void)out_size;

  hipMemsetAsync(count, 0, 4, stream);
  hipMemsetAsync(aggr, 0, (size_t)B_ * N_ * D_ * 4, stream);

  k_init_h<<<B_ * N_ * D_ / 4 / 256, 256, 0, stream>>>(dists, noise, dist_table, h);
  k_compact<<<B_ * E_ / 256, 256, 0, stream>>>(edge_mask, count, list);
  k_tables<<<L_ * 210, 128, 0, stream>>>(dist_table, rel_table, msg_W, msg_b, T3b, T4);
  k_wbt_msg<<<L_ * D_ * KEFF / 256, 256, 0, stream>>>(msg_W, Wbt_msg);
  k_wbt_upd<<<L_ * D_ * D_ / 256, 256, 0, stream>>>(upd_W, Wbt_upd);

  for (int k = 0; k < L_; ++k) {
    k_msg<<<B_ * E_ / 64, 256, 0, stream>>>(count, list, edge_index, rels, dists, h,
        rel_table, conf, Wbt_msg + (size_t)k * D_ * KEFF,
        T3b + k * 10 * D_, T4 + k * R_ * D_, aggr);
    k_upd<<<B_ * N_ / 64, 256, 0, stream>>>(aggr, Wbt_upd + (size_t)k * D_ * D_,
        upd_b + k * D_, h);
  }
  k_score<<<B_ * N_ / 4, 256, 0, stream>>>(h, node_mask, r_query, att_W, att_b, scores);
  k_top<<<B_, 1024, 0, stream>>>(scores, h, node_mask, out);
}

// Round 6
// 544.581 us; speedup vs baseline: 1.1110x; 1.1110x over previous
//
#include <hip/hip_runtime.h>
#include <hip/hip_bf16.h>
#include <math.h>

#define B_ 8
#define N_ 8192
#define E_ 16384
#define D_ 128
#define R_ 200
#define M_ 20
#define L_ 3
#define KEFF 384   // comp(128) + h_src(128) + conf(128); dist/rel blocks folded into tables
#define LDA 392    // A-tile LDS row stride (shorts): 784B rows, 16B-aligned, ~2-way banks
#define LDU 136    // upd-tile LDS row stride (shorts): 272B rows

typedef __attribute__((ext_vector_type(8))) short bf16x8;
typedef __attribute__((ext_vector_type(4))) float f32x4;

__device__ __forceinline__ short f2b(float f) {
  union { __hip_bfloat16 b; short s; } u;
  u.b = __float2bfloat16(f);
  return u.s;
}
__device__ __forceinline__ bf16x8 pack8(float4 x, float4 y) {
  bf16x8 r;
  r[0] = f2b(x.x); r[1] = f2b(x.y); r[2] = f2b(x.z); r[3] = f2b(x.w);
  r[4] = f2b(y.x); r[5] = f2b(y.y); r[6] = f2b(y.z); r[7] = f2b(y.w);
  return r;
}
__device__ __forceinline__ bf16x8 pack8mul(float4 x, float4 rx, float4 y, float4 ry) {
  bf16x8 r;
  r[0] = f2b(x.x * rx.x); r[1] = f2b(x.y * rx.y); r[2] = f2b(x.z * rx.z); r[3] = f2b(x.w * rx.w);
  r[4] = f2b(y.x * ry.x); r[5] = f2b(y.y * ry.y); r[6] = f2b(y.z * ry.z); r[7] = f2b(y.w * ry.w);
  return r;
}

// ---------------- h init: h = dist_table[clip(dists)] + 0.1*noise ----------------
__global__ __launch_bounds__(256) void k_init_h(const int* __restrict__ dists,
    const float* __restrict__ noise, const float* __restrict__ dist_table,
    float* __restrict__ h) {
  int i = blockIdx.x * 256 + threadIdx.x;   // float4 index, total B*N*D/4
  int row = i >> 5;                          // D/4 = 32 float4 per row
  int d4 = i & 31;
  int dc = dists[row]; dc = dc < 0 ? 0 : (dc > 9 ? 9 : dc);
  const float4 t = *(const float4*)&dist_table[dc * D_ + d4 * 4];
  const float4 nz = *(const float4*)&noise[(size_t)i * 4];
  float4 o;
  o.x = t.x + 0.1f * nz.x; o.y = t.y + 0.1f * nz.y;
  o.z = t.z + 0.1f * nz.z; o.w = t.w + 0.1f * nz.w;
  *(float4*)&h[(size_t)i * 4] = o;
}

// ---------------- active-edge compaction ----------------
__global__ __launch_bounds__(256) void k_compact(const int* __restrict__ edge_mask,
    int* __restrict__ count, int* __restrict__ list) {
  int i = blockIdx.x * 256 + threadIdx.x;
  bool act = edge_mask[i] != 0;
  unsigned long long m = __ballot(act);
  int lane = threadIdx.x & 63;
  int base = 0;
  if (lane == 0) base = atomicAdd(count, __popcll(m));
  base = __shfl(base, 0);
  if (act) list[base + __popcll(m & ((1ull << lane) - 1ull))] = i;  // i = b*E+e
}

// ------- T3b[k][t][d] = dist_table[t]@W3[k] + msg_b[k],  T4[k][r][d] = rel_table[r]@W4[k]
__global__ __launch_bounds__(128) void k_tables(const float* __restrict__ dist_table,
    const float* __restrict__ rel_table, const float* __restrict__ msg_W,
    const float* __restrict__ msg_b, float* __restrict__ T3b, float* __restrict__ T4) {
  int k = blockIdx.x / 210;
  int r = blockIdx.x % 210;
  int d = threadIdx.x;
  if (r < 10) {
    float acc = msg_b[k * D_ + d];
    for (int f = 0; f < D_; ++f)
      acc = fmaf(dist_table[r * D_ + f], msg_W[(size_t)(k * 640 + 256 + f) * D_ + d], acc);
    T3b[(k * 10 + r) * D_ + d] = acc;
  } else {
    int rr = r - 10;
    float acc = 0.f;
    for (int f = 0; f < D_; ++f)
      acc = fmaf(rel_table[rr * D_ + f], msg_W[(size_t)(k * 640 + 384 + f) * D_ + d], acc);
    T4[(k * R_ + rr) * D_ + d] = acc;
  }
}

// ------- Wbt_msg[k][n][fe] (bf16): effective msg weight, n-major so B-frags read contiguous
__global__ __launch_bounds__(256) void k_wbt_msg(const float* __restrict__ msg_W,
    short* __restrict__ Wbt) {
  int idx = blockIdx.x * 256 + threadIdx.x;   // L*128*384
  int fe = idx % KEFF;
  int t = idx / KEFF;
  int n = t & 127;
  int k = t >> 7;
  int row = fe < 256 ? fe : fe + 256;         // skip dist(256:384)/rel(384:512) blocks
  Wbt[idx] = f2b(msg_W[(size_t)(k * 640 + row) * D_ + n]);
}

__global__ __launch_bounds__(256) void k_wbt_upd(const float* __restrict__ upd_W,
    short* __restrict__ Wbt) {
  int idx = blockIdx.x * 256 + threadIdx.x;   // L*128*128, layout [k][n][f]
  int f = idx & 127;
  int t = idx >> 7;
  int n = t & 127;
  int k = t >> 7;
  Wbt[idx] = f2b(upd_W[(size_t)(k * D_ + f) * D_ + n]);
}

// ---------------- message GEMM (MFMA) + scatter ----------------
// 64 edges x 128 out per block; 4 waves each own a 32x64 tile. The whole 64x384 A-tile
// is staged to LDS in ONE cooperative phase (h loaded once; comp packed in-regs), then
// ONE barrier, then 12 barrier-free K-steps (A from LDS, B from L2-hot weights).
__global__ __launch_bounds__(256, 3) void k_msg(
    const int* __restrict__ count_p, const int* __restrict__ list,
    const int* __restrict__ edge_index, const int* __restrict__ rels,
    const int* __restrict__ dists, const float* __restrict__ h,
    const float* __restrict__ rel_table, const float* __restrict__ conf,
    const short* __restrict__ Wbt,    // [128][384] bf16 (n-major), this layer
    const float* __restrict__ T3b,    // [10][128]
    const float* __restrict__ T4,     // [200][128]
    float* __restrict__ aggr) {
  int cnt = *count_p;
  int base = blockIdx.x * 64;
  if (base >= cnt) return;
  int ne = min(64, cnt - base);
  __shared__ __align__(16) short sA[64 * LDA];
  __shared__ int sMeta[64][5];                 // hsrc_row, id(conf row), aggr_row, dclip, rel
  int tid = threadIdx.x;
  if (tid < 64) {
    int t = tid < ne ? tid : 0;                // pad rows alias edge 0 (valid addresses)
    int id = list[base + t];
    int b = id >> 14;                          // E = 2^14
    int e = id & (E_ - 1);
    int src = edge_index[(b * 2) * E_ + e];
    int tgt = edge_index[(b * 2 + 1) * E_ + e];
    int dc = dists[b * N_ + src];
    dc = dc < 0 ? 0 : (dc > 9 ? 9 : dc);
    sMeta[tid][0] = b * N_ + src;
    sMeta[tid][1] = id;
    sMeta[tid][2] = b * N_ + tgt;
    sMeta[tid][3] = dc;
    sMeta[tid][4] = rels[id];
  }
  __syncthreads();
  // ---- stage whole A-tile: thread (i=tid>>2, q=tid&3) covers 32 K-cols of row i ----
  {
    int i = tid >> 2, q = tid & 3;
    const float4* ph = (const float4*)(h + (size_t)sMeta[i][0] * D_ + q * 32);
    const float4* pr = (const float4*)(rel_table + (size_t)sMeta[i][4] * D_ + q * 32);
    const float4* pc = (const float4*)(conf + (size_t)sMeta[i][1] * D_ + q * 32);
    float4 hv[8], rv[8], cv[8];
#pragma unroll
    for (int j = 0; j < 8; ++j) hv[j] = ph[j];
#pragma unroll
    for (int j = 0; j < 8; ++j) rv[j] = pr[j];
#pragma unroll
    for (int j = 0; j < 8; ++j) cv[j] = pc[j];
    short* rowp = &sA[i * LDA];
#pragma unroll
    for (int j = 0; j < 4; ++j) {
      *(bf16x8*)&rowp[q * 32 + j * 8]       = pack8mul(hv[2*j], rv[2*j], hv[2*j+1], rv[2*j+1]); // comp
      *(bf16x8*)&rowp[128 + q * 32 + j * 8] = pack8(hv[2*j], hv[2*j+1]);                        // h_src
      *(bf16x8*)&rowp[256 + q * 32 + j * 8] = pack8(cv[2*j], cv[2*j+1]);                        // conf
    }
  }
  __syncthreads();
  // ---- MFMA: 12 barrier-free K-steps of 32 ----
  int lane = tid & 63, wv = tid >> 6;
  int wm = wv >> 1, wn = wv & 1;               // wave tile: rows [wm*32,+32), cols [wn*64,+64)
  int g = lane >> 4, cl = lane & 15;
  const short* pa0 = &sA[(wm * 32 + cl) * LDA];
  const short* pa1 = pa0 + 16 * LDA;
  const short* wb = Wbt + (size_t)(wn * 64 + cl) * KEFF;   // tn adds tn*16*KEFF

  f32x4 acc[2][4];
  f32x4 zz = {0.f, 0.f, 0.f, 0.f};
#pragma unroll
  for (int tm = 0; tm < 2; ++tm)
#pragma unroll
    for (int tn = 0; tn < 4; ++tn) acc[tm][tn] = zz;

#pragma unroll
  for (int kstep = 0; kstep < 12; ++kstep) {
    int o = kstep * 32 + g * 8;
    bf16x8 a0 = *(const bf16x8*)&pa0[o];
    bf16x8 a1 = *(const bf16x8*)&pa1[o];
    const short* wk = wb + o;
    bf16x8 b0 = *(const bf16x8*)(wk);
    bf16x8 b1 = *(const bf16x8*)(wk + 16 * KEFF);
    bf16x8 b2 = *(const bf16x8*)(wk + 32 * KEFF);
    bf16x8 b3 = *(const bf16x8*)(wk + 48 * KEFF);
    acc[0][0] = __builtin_amdgcn_mfma_f32_16x16x32_bf16(a0, b0, acc[0][0], 0, 0, 0);
    acc[0][1] = __builtin_amdgcn_mfma_f32_16x16x32_bf16(a0, b1, acc[0][1], 0, 0, 0);
    acc[0][2] = __builtin_amdgcn_mfma_f32_16x16x32_bf16(a0, b2, acc[0][2], 0, 0, 0);
    acc[0][3] = __builtin_amdgcn_mfma_f32_16x16x32_bf16(a0, b3, acc[0][3], 0, 0, 0);
    acc[1][0] = __builtin_amdgcn_mfma_f32_16x16x32_bf16(a1, b0, acc[1][0], 0, 0, 0);
    acc[1][1] = __builtin_amdgcn_mfma_f32_16x16x32_bf16(a1, b1, acc[1][1], 0, 0, 0);
    acc[1][2] = __builtin_amdgcn_mfma_f32_16x16x32_bf16(a1, b2, acc[1][2], 0, 0, 0);
    acc[1][3] = __builtin_amdgcn_mfma_f32_16x16x32_bf16(a1, b3, acc[1][3], 0, 0, 0);
  }
  // ---- epilogue: bias + relu + atomic scatter ----
#pragma unroll
  for (int tm = 0; tm < 2; ++tm)
#pragma unroll
    for (int reg = 0; reg < 4; ++reg) {
      int edge = wm * 32 + tm * 16 + g * 4 + reg;   // C/D: row=(lane>>4)*4+reg, col=lane&15
      if (edge < ne) {
        int arow = sMeta[edge][2];
        int dc = sMeta[edge][3];
        int rl = sMeta[edge][4];
#pragma unroll
        for (int tn = 0; tn < 4; ++tn) {
          int n = wn * 64 + tn * 16 + cl;
          float bias = T3b[dc * D_ + n] + T4[rl * D_ + n];
          float vv = fmaxf(acc[tm][tn][reg] + bias, 0.f);
          unsafeAtomicAdd(&aggr[(size_t)arow * D_ + n], vv);
        }
      }
    }
}

// ---------------- node update (MFMA): h = aggr@upd_W + upd_b + h ; aggr = 0 ----------------
// Same single-stage structure: 64 rows staged+re-zeroed in one phase, one barrier, 4 K-steps.
__global__ __launch_bounds__(256, 4) void k_upd(
    float* __restrict__ aggr, const short* __restrict__ Wbt,   // [128][128] bf16 n-major
    const float* __restrict__ upd_b, float* __restrict__ h) {
  int base = blockIdx.x * 64;
  int tid = threadIdx.x;
  __shared__ __align__(16) short sU[64 * LDU];
  {
    int i = tid >> 2, q = tid & 3;
    float4* ap = (float4*)(aggr + (size_t)(base + i) * D_ + q * 32);
    float4 av[8];
    float4 z4 = make_float4(0.f, 0.f, 0.f, 0.f);
#pragma unroll
    for (int j = 0; j < 8; ++j) av[j] = ap[j];
#pragma unroll
    for (int j = 0; j < 8; ++j) ap[j] = z4;    // re-zero for next layer
    short* rowp = &sU[i * LDU];
#pragma unroll
    for (int j = 0; j < 4; ++j)
      *(bf16x8*)&rowp[q * 32 + j * 8] = pack8(av[2*j], av[2*j+1]);
  }
  __syncthreads();
  int lane = tid & 63, wv = tid >> 6;
  int wm = wv >> 1, wn = wv & 1;
  int g = lane >> 4, cl = lane & 15;
  const short* pa0 = &sU[(wm * 32 + cl) * LDU];
  const short* pa1 = pa0 + 16 * LDU;
  const short* wb = Wbt + (size_t)(wn * 64 + cl) * D_;

  f32x4 acc[2][4];
  f32x4 zz = {0.f, 0.f, 0.f, 0.f};
#pragma unroll
  for (int tm = 0; tm < 2; ++tm)
#pragma unroll
    for (int tn = 0; tn < 4; ++tn) acc[tm][tn] = zz;

#pragma unroll
  for (int kstep = 0; kstep < 4; ++kstep) {
    int o = kstep * 32 + g * 8;
    bf16x8 a0 = *(const bf16x8*)&pa0[o];
    bf16x8 a1 = *(const bf16x8*)&pa1[o];
    const short* wk = wb + o;
    bf16x8 b0 = *(const bf16x8*)(wk);
    bf16x8 b1 = *(const bf16x8*)(wk + 16 * D_);
    bf16x8 b2 = *(const bf16x8*)(wk + 32 * D_);
    bf16x8 b3 = *(const bf16x8*)(wk + 48 * D_);
    acc[0][0] = __builtin_amdgcn_mfma_f32_16x16x32_bf16(a0, b0, acc[0][0], 0, 0, 0);
    acc[0][1] = __builtin_amdgcn_mfma_f32_16x16x32_bf16(a0, b1, acc[0][1], 0, 0, 0);
    acc[0][2] = __builtin_amdgcn_mfma_f32_16x16x32_bf16(a0, b2, acc[0][2], 0, 0, 0);
    acc[0][3] = __builtin_amdgcn_mfma_f32_16x16x32_bf16(a0, b3, acc[0][3], 0, 0, 0);
    acc[1][0] = __builtin_amdgcn_mfma_f32_16x16x32_bf16(a1, b0, acc[1][0], 0, 0, 0);
    acc[1][1] = __builtin_amdgcn_mfma_f32_16x16x32_bf16(a1, b1, acc[1][1], 0, 0, 0);
    acc[1][2] = __builtin_amdgcn_mfma_f32_16x16x32_bf16(a1, b2, acc[1][2], 0, 0, 0);
    acc[1][3] = __builtin_amdgcn_mfma_f32_16x16x32_bf16(a1, b3, acc[1][3], 0, 0, 0);
  }
#pragma unroll
  for (int tm = 0; tm < 2; ++tm)
#pragma unroll
    for (int reg = 0; reg < 4; ++reg) {
      int grow = base + wm * 32 + tm * 16 + g * 4 + reg;
#pragma unroll
      for (int tn = 0; tn < 4; ++tn) {
        int n = wn * 64 + tn * 16 + cl;
        size_t gi = (size_t)grow * D_ + n;
        h[gi] = acc[tm][tn][reg] + upd_b[n] + h[gi];
      }
    }
}

// ---------------- scores: one wave per node, full att_in dot ----------------
__global__ __launch_bounds__(256) void k_score(const float* __restrict__ h,
    const int* __restrict__ node_mask, const float* __restrict__ r_query,
    const float* __restrict__ att_W, const float* __restrict__ att_b,
    float* __restrict__ sSg) {
  int wv = threadIdx.x >> 6, lane = threadIdx.x & 63;
  int node = blockIdx.x * 4 + wv;              // [0, B*N)
  int b = node >> 13;                           // N = 2^13
  float s;
  if (node_mask[node] == 0) {
    s = -1e9f;
  } else {
    float2 hv = *(const float2*)&h[(size_t)node * D_ + lane * 2];
    float2 w0 = *(const float2*)&att_W[lane * 2];
    float2 w1 = *(const float2*)&att_W[D_ + lane * 2];
    float2 rq = *(const float2*)&r_query[b * D_ + lane * 2];
    float v = hv.x * w0.x + hv.y * w0.y + rq.x * w1.x + rq.y * w1.y;
#pragma unroll
    for (int off = 32; off > 0; off >>= 1) v += __shfl_xor(v, off);
    v += att_b[0];
    s = v > 0.f ? v : 0.01f * v;
  }
  if (lane == 0) sSg[node] = s;
}

// ---------------- per-batch: softmax stats + top-20 + outputs ----------------
__global__ __launch_bounds__(1024) void k_top(const float* __restrict__ sSg,
    const float* __restrict__ h, const int* __restrict__ node_mask,
    float* __restrict__ out) {
  int b = blockIdx.x;
  int tid = threadIdx.x, lane = tid & 63, wv = tid >> 6;   // 16 waves
  __shared__ float sS[N_];
  __shared__ float sRw[16];
  __shared__ float sSegV[16];
  __shared__ int sSegI[16];
  __shared__ float sTopV[M_];
  __shared__ int sTopI[M_];
  __shared__ float sMax, sSum;
  const float4* gp = (const float4*)&sSg[(size_t)b * N_];
#pragma unroll
  for (int r = 0; r < 2; ++r) {
    float4 x = gp[tid + r * 1024];
    *(float4*)&sS[(tid + r * 1024) * 4] = x;
  }
  __syncthreads();
  // block max
  float lm = -INFINITY;
  for (int n = tid; n < N_; n += 1024) lm = fmaxf(lm, sS[n]);
#pragma unroll
  for (int off = 32; off > 0; off >>= 1) lm = fmaxf(lm, __shfl_xor(lm, off));
  if (lane == 0) sRw[wv] = lm;
  __syncthreads();
  if (tid == 0) {
    float m = sRw[0];
    for (int i = 1; i < 16; ++i) m = fmaxf(m, sRw[i]);
    sMax = m;
  }
  __syncthreads();
  float mx = sMax;
  // softmax denom
  float ls = 0.f;
  for (int n = tid; n < N_; n += 1024) ls += expf(sS[n] - mx);
#pragma unroll
  for (int off = 32; off > 0; off >>= 1) ls += __shfl_xor(ls, off);
  if (lane == 0) sRw[wv] = ls;
  __syncthreads();
  if (tid == 0) {
    float s = 0.f;
    for (int i = 0; i < 16; ++i) s += sRw[i];
    sSum = s;
  }
  // per-wave segment argmax (segment = 512 nodes), ties -> lowest index
  {
    float bv = -INFINITY; int bi = 0;
    int s0 = wv * 512;
    for (int t2 = 0; t2 < 8; ++t2) {
      int n = s0 + lane + t2 * 64;
      float x = sS[n];
      if (x > bv) { bv = x; bi = n; }
    }
#pragma unroll
    for (int off = 32; off > 0; off >>= 1) {
      float vv = __shfl_xor(bv, off); int ii = __shfl_xor(bi, off);
      if (vv > bv || (vv == bv && ii < bi)) { bv = vv; bi = ii; }
    }
    if (lane == 0) { sSegV[wv] = bv; sSegI[wv] = bi; }
  }
  __syncthreads();
  // top-20: pick best segment, knock out, rescan only that segment
  for (int j = 0; j < M_; ++j) {
    if (wv == 0) {
      float bv = (lane < 16) ? sSegV[lane] : -INFINITY;
      int bi = (lane < 16) ? sSegI[lane] : 0x7fffffff;
#pragma unroll
      for (int off = 32; off > 0; off >>= 1) {
        float vv = __shfl_xor(bv, off); int ii = __shfl_xor(bi, off);
        if (vv > bv || (vv == bv && ii < bi)) { bv = vv; bi = ii; }
      }
      if (lane == 0) { sTopV[j] = bv; sTopI[j] = bi; sS[bi] = -INFINITY; }
    }
    __syncthreads();
    int seg = sTopI[j] >> 9;
    if (wv == seg) {
      float bv = -INFINITY; int bi = 0;
      int s0 = wv * 512;
      for (int t2 = 0; t2 < 8; ++t2) {
        int n = s0 + lane + t2 * 64;
        float x = sS[n];
        if (x > bv) { bv = x; bi = n; }
      }
#pragma unroll
      for (int off = 32; off > 0; off >>= 1) {
        float vv = __shfl_xor(bv, off); int ii = __shfl_xor(bi, off);
        if (vv > bv || (vv == bv && ii < bi)) { bv = vv; bi = ii; }
      }
      if (lane == 0) { sSegV[wv] = bv; sSegI[wv] = bi; }
    }
    __syncthreads();
  }
  float sum = sSum;
  // t_state = (h*mask)[b,0,:]
  if (tid < D_) {
    float vv = node_mask[b * N_] ? h[(size_t)b * N_ * D_ + tid] : 0.f;
    out[B_ * M_ * D_ + b * D_ + tid] = vv;
  }
  // H_evd[b,j,:] = (h*mask)[b,idx_j,:] * alpha_j
  for (int s2 = tid; s2 < M_ * D_; s2 += 1024) {
    int j = s2 >> 7, d = s2 & 127;
    int idx = sTopI[j];
    float alpha = expf(sTopV[j] - mx) / sum;
    float hv = h[((size_t)b * N_ + idx) * D_ + d];
    if (!node_mask[b * N_ + idx]) hv = 0.f;
    out[(b * M_ + j) * D_ + d] = hv * alpha;
  }
}

// ---------------- host ----------------
extern "C" void kernel_launch(void* const* d_in, const int* in_sizes, int n_in,
                              void* d_out, int out_size, void* d_ws, size_t ws_size,
                              hipStream_t stream) {
  const int*   dists      = (const int*)d_in[0];
  const int*   edge_index = (const int*)d_in[1];
  const int*   rels       = (const int*)d_in[2];
  const int*   node_mask  = (const int*)d_in[3];
  const int*   edge_mask  = (const int*)d_in[4];
  const float* r_query    = (const float*)d_in[5];
  const float* conf       = (const float*)d_in[6];
  const float* noise      = (const float*)d_in[7];
  const float* dist_table = (const float*)d_in[8];
  const float* rel_table  = (const float*)d_in[9];
  const float* msg_W      = (const float*)d_in[10];
  const float* msg_b      = (const float*)d_in[11];
  const float* upd_W      = (const float*)d_in[12];
  const float* upd_b      = (const float*)d_in[13];
  const float* att_W      = (const float*)d_in[14];
  const float* att_b      = (const float*)d_in[15];
  float* out = (float*)d_out;

  char* ws = (char*)d_ws;
  size_t off = 0;
  auto alloc = [&](size_t bytes) {
    void* p = ws + off;
    off = (off + bytes + 255) & ~(size_t)255;
    return p;
  };
  int*   count   = (int*)alloc(4);
  int*   list    = (int*)alloc((size_t)B_ * E_ * 4);
  float* h       = (float*)alloc((size_t)B_ * N_ * D_ * 4);
  float* aggr    = (float*)alloc((size_t)B_ * N_ * D_ * 4);
  short* Wbt_msg = (short*)alloc((size_t)L_ * D_ * KEFF * 2);
  short* Wbt_upd = (short*)alloc((size_t)L_ * D_ * D_ * 2);
  float* T3b     = (float*)alloc((size_t)L_ * 10 * D_ * 4);
  float* T4      = (float*)alloc((size_t)L_ * R_ * D_ * 4);
  float* scores  = (float*)alloc((size_t)B_ * N_ * 4);
  (void)ws_size; (void)in_sizes; (void)n_in; (void)out_size;

  hipMemsetAsync(count, 0, 4, stream);
  hipMemsetAsync(aggr, 0, (size_t)B_ * N_ * D_ * 4, stream);

  k_init_h<<<B_ * N_ * D_ / 4 / 256, 256, 0, stream>>>(dists, noise, dist_table, h);
  k_compact<<<B_ * E_ / 256, 256, 0, stream>>>(edge_mask, count, list);
  k_tables<<<L_ * 210, 128, 0, stream>>>(dist_table, rel_table, msg_W, msg_b, T3b, T4);
  k_wbt_msg<<<L_ * D_ * KEFF / 256, 256, 0, stream>>>(msg_W, Wbt_msg);
  k_wbt_upd<<<L_ * D_ * D_ / 256, 256, 0, stream>>>(upd_W, Wbt_upd);

  for (int k = 0; k < L_; ++k) {
    k_msg<<<B_ * E_ / 64, 256, 0, stream>>>(count, list, edge_index, rels, dists, h,
        rel_table, conf, Wbt_msg + (size_t)k * D_ * KEFF,
        T3b + k * 10 * D_, T4 + k * R_ * D_, aggr);
    k_upd<<<B_ * N_ / 64, 256, 0, stream>>>(aggr, Wbt_upd + (size_t)k * D_ * D_,
        upd_b + k * D_, h);
  }
  k_score<<<B_ * N_ / 4, 256, 0, stream>>>(h, node_mask, r_query, att_W, att_b, scores);
  k_top<<<B_, 1024, 0, stream>>>(scores, h, node_mask, out);
}

// Round 9
// 475.155 us; speedup vs baseline: 1.2733x; 1.1461x over previous
//
#include <hip/hip_runtime.h>
#include <hip/hip_bf16.h>
#include <math.h>

#define B_ 8
#define N_ 8192
#define E_ 16384
#define D_ 128
#define R_ 200
#define M_ 20
#define L_ 3
#define KEFF 384   // comp(128) + h_src(128) + conf(128); dist/rel blocks folded into tables
#define LDA 392    // A-tile LDS row stride (shorts): 784B rows, 16B-aligned, 2-way banks
#define LDU 136    // upd-tile LDS row stride (shorts): 272B rows

typedef __attribute__((ext_vector_type(8))) short bf16x8;
typedef __attribute__((ext_vector_type(4))) float f32x4;

__device__ __forceinline__ short f2b(float f) {
  union { __hip_bfloat16 b; short s; } u;
  u.b = __float2bfloat16(f);
  return u.s;
}
__device__ __forceinline__ bf16x8 pack8(float4 x, float4 y) {
  bf16x8 r;
  r[0] = f2b(x.x); r[1] = f2b(x.y); r[2] = f2b(x.z); r[3] = f2b(x.w);
  r[4] = f2b(y.x); r[5] = f2b(y.y); r[6] = f2b(y.z); r[7] = f2b(y.w);
  return r;
}
__device__ __forceinline__ bf16x8 pack8mul(float4 x, float4 rx, float4 y, float4 ry) {
  bf16x8 r;
  r[0] = f2b(x.x * rx.x); r[1] = f2b(x.y * rx.y); r[2] = f2b(x.z * rx.z); r[3] = f2b(x.w * rx.w);
  r[4] = f2b(y.x * ry.x); r[5] = f2b(y.y * ry.y); r[6] = f2b(y.z * ry.z); r[7] = f2b(y.w * ry.w);
  return r;
}

// ---------------- h init: h = dist_table[clip(dists)] + 0.1*noise ----------------
__global__ __launch_bounds__(256) void k_init_h(const int* __restrict__ dists,
    const float* __restrict__ noise, const float* __restrict__ dist_table,
    float* __restrict__ h) {
  int i = blockIdx.x * 256 + threadIdx.x;   // float4 index, total B*N*D/4
  int row = i >> 5;                          // D/4 = 32 float4 per row
  int d4 = i & 31;
  int dc = dists[row]; dc = dc < 0 ? 0 : (dc > 9 ? 9 : dc);
  const float4 t = *(const float4*)&dist_table[dc * D_ + d4 * 4];
  const float4 nz = *(const float4*)&noise[(size_t)i * 4];
  float4 o;
  o.x = t.x + 0.1f * nz.x; o.y = t.y + 0.1f * nz.y;
  o.z = t.z + 0.1f * nz.z; o.w = t.w + 0.1f * nz.w;
  *(float4*)&h[(size_t)i * 4] = o;
}

// ---------------- active-edge compaction + per-target histogram ----------------
__global__ __launch_bounds__(256) void k_compact(const int* __restrict__ edge_mask,
    const int* __restrict__ edge_index, int* __restrict__ count,
    int* __restrict__ list, int* __restrict__ cnt) {
  int i = blockIdx.x * 256 + threadIdx.x;
  bool act = edge_mask[i] != 0;
  unsigned long long m = __ballot(act);
  int lane = threadIdx.x & 63;
  int base = 0;
  if (lane == 0) base = atomicAdd(count, __popcll(m));
  base = __shfl(base, 0);
  if (act) {
    list[base + __popcll(m & ((1ull << lane) - 1ull))] = i;  // i = b*E+e
    int b = i >> 14, e = i & (E_ - 1);
    int tgt = edge_index[(b * 2 + 1) * E_ + e];
    atomicAdd(&cnt[b * N_ + tgt], 1);
  }
}

// ---------------- CSR scan (65536 entries): A=block sums, B=scan sums, C=final ----------------
__global__ __launch_bounds__(256) void k_scanA(const int* __restrict__ cnt,
    int* __restrict__ bsum) {
  __shared__ int s[4];
  int v = cnt[blockIdx.x * 256 + threadIdx.x];
#pragma unroll
  for (int o = 32; o > 0; o >>= 1) v += __shfl_xor(v, o);
  if ((threadIdx.x & 63) == 0) s[threadIdx.x >> 6] = v;
  __syncthreads();
  if (threadIdx.x == 0) bsum[blockIdx.x] = s[0] + s[1] + s[2] + s[3];
}

__global__ __launch_bounds__(256) void k_scanB(const int* __restrict__ bsum,
    int* __restrict__ boff) {
  __shared__ int s[256];
  int t = threadIdx.x;
  s[t] = bsum[t];
  __syncthreads();
  for (int o = 1; o < 256; o <<= 1) {
    int v = (t >= o) ? s[t - o] : 0;
    __syncthreads();
    s[t] += v;
    __syncthreads();
  }
  boff[t] = (t == 0) ? 0 : s[t - 1];
}

__global__ __launch_bounds__(256) void k_scanC(const int* __restrict__ cnt,
    const int* __restrict__ boff, int* __restrict__ off, int* __restrict__ cur) {
  __shared__ int s[256];
  int t = threadIdx.x;
  int gi = blockIdx.x * 256 + t;
  int v = cnt[gi];
  s[t] = v;
  __syncthreads();
  for (int o = 1; o < 256; o <<= 1) {
    int u = (t >= o) ? s[t - o] : 0;
    __syncthreads();
    s[t] += u;
    __syncthreads();
  }
  int excl = s[t] - v + boff[blockIdx.x];
  off[gi] = excl;
  cur[gi] = excl;
}

__global__ __launch_bounds__(256) void k_fill(const int* __restrict__ count_p,
    const int* __restrict__ list, const int* __restrict__ edge_index,
    int* __restrict__ cur, int* __restrict__ csr) {
  int j = blockIdx.x * 256 + threadIdx.x;
  if (j >= *count_p) return;
  int id = list[j];
  int b = id >> 14, e = id & (E_ - 1);
  int tgt = edge_index[(b * 2 + 1) * E_ + e];
  int pos = atomicAdd(&cur[b * N_ + tgt], 1);
  csr[pos] = j;
}

// ------- T3b[k][t][d] = dist_table[t]@W3[k] + msg_b[k],  T4[k][r][d] = rel_table[r]@W4[k]
__global__ __launch_bounds__(128) void k_tables(const float* __restrict__ dist_table,
    const float* __restrict__ rel_table, const float* __restrict__ msg_W,
    const float* __restrict__ msg_b, float* __restrict__ T3b, float* __restrict__ T4) {
  int k = blockIdx.x / 210;
  int r = blockIdx.x % 210;
  int d = threadIdx.x;
  if (r < 10) {
    float acc = msg_b[k * D_ + d];
    for (int f = 0; f < D_; ++f)
      acc = fmaf(dist_table[r * D_ + f], msg_W[(size_t)(k * 640 + 256 + f) * D_ + d], acc);
    T3b[(k * 10 + r) * D_ + d] = acc;
  } else {
    int rr = r - 10;
    float acc = 0.f;
    for (int f = 0; f < D_; ++f)
      acc = fmaf(rel_table[rr * D_ + f], msg_W[(size_t)(k * 640 + 384 + f) * D_ + d], acc);
    T4[(k * R_ + rr) * D_ + d] = acc;
  }
}

// ------- Wbt_msg[k][n][fe] (bf16): effective msg weight, n-major so B-frags read contiguous
__global__ __launch_bounds__(256) void k_wbt_msg(const float* __restrict__ msg_W,
    short* __restrict__ Wbt) {
  int idx = blockIdx.x * 256 + threadIdx.x;   // L*128*384
  int fe = idx % KEFF;
  int t = idx / KEFF;
  int n = t & 127;
  int k = t >> 7;
  int row = fe < 256 ? fe : fe + 256;         // skip dist(256:384)/rel(384:512) blocks
  Wbt[idx] = f2b(msg_W[(size_t)(k * 640 + row) * D_ + n]);
}

__global__ __launch_bounds__(256) void k_wbt_upd(const float* __restrict__ upd_W,
    short* __restrict__ Wbt) {
  int idx = blockIdx.x * 256 + threadIdx.x;   // L*128*128, layout [k][n][f]
  int f = idx & 127;
  int t = idx >> 7;
  int n = t & 127;
  int k = t >> 7;
  Wbt[idx] = f2b(upd_W[(size_t)(k * D_ + f) * D_ + n]);
}

// ---------------- message GEMM (MFMA): dense per-edge msg store, NO atomics ----------------
__global__ __launch_bounds__(256, 3) void k_msg(
    const int* __restrict__ count_p, const int* __restrict__ list,
    const int* __restrict__ edge_index, const int* __restrict__ rels,
    const int* __restrict__ dists, const float* __restrict__ h,
    const float* __restrict__ rel_table, const float* __restrict__ conf,
    const short* __restrict__ Wbt,    // [128][384] bf16 (n-major), this layer
    const float* __restrict__ T3b,    // [10][128]
    const float* __restrict__ T4,     // [200][128]
    float* __restrict__ msgbuf) {     // [B*E][128] (first *count rows used)
  int cnt = *count_p;
  int base = blockIdx.x * 64;
  if (base >= cnt) return;
  int ne = min(64, cnt - base);
  __shared__ __align__(16) short sA[64 * LDA];
  __shared__ int sMeta[64][4];                 // hsrc_row, id(conf row), dclip, rel
  int tid = threadIdx.x;
  if (tid < 64) {
    int t = tid < ne ? tid : 0;                // pad rows alias edge 0 (valid addresses)
    int id = list[base + t];
    int b = id >> 14;                          // E = 2^14
    int e = id & (E_ - 1);
    int src = edge_index[(b * 2) * E_ + e];
    int dc = dists[b * N_ + src];
    dc = dc < 0 ? 0 : (dc > 9 ? 9 : dc);
    sMeta[tid][0] = b * N_ + src;
    sMeta[tid][1] = id;
    sMeta[tid][2] = dc;
    sMeta[tid][3] = rels[id];
  }
  __syncthreads();
  // ---- stage whole A-tile: thread (i=tid>>2, q=tid&3) covers 32 K-cols of row i ----
  {
    int i = tid >> 2, q = tid & 3;
    const float4* ph = (const float4*)(h + (size_t)sMeta[i][0] * D_ + q * 32);
    const float4* pr = (const float4*)(rel_table + (size_t)sMeta[i][3] * D_ + q * 32);
    const float4* pc = (const float4*)(conf + (size_t)sMeta[i][1] * D_ + q * 32);
    float4 hv[8], rv[8], cv[8];
#pragma unroll
    for (int j = 0; j < 8; ++j) hv[j] = ph[j];
#pragma unroll
    for (int j = 0; j < 8; ++j) rv[j] = pr[j];
#pragma unroll
    for (int j = 0; j < 8; ++j) cv[j] = pc[j];
    short* rowp = &sA[i * LDA];
#pragma unroll
    for (int j = 0; j < 4; ++j) {
      *(bf16x8*)&rowp[q * 32 + j * 8]       = pack8mul(hv[2*j], rv[2*j], hv[2*j+1], rv[2*j+1]); // comp
      *(bf16x8*)&rowp[128 + q * 32 + j * 8] = pack8(hv[2*j], hv[2*j+1]);                        // h_src
      *(bf16x8*)&rowp[256 + q * 32 + j * 8] = pack8(cv[2*j], cv[2*j+1]);                        // conf
    }
  }
  __syncthreads();
  // ---- MFMA: 12 barrier-free K-steps of 32 ----
  int lane = tid & 63, wv = tid >> 6;
  int wm = wv >> 1, wn = wv & 1;               // wave tile: rows [wm*32,+32), cols [wn*64,+64)
  int g = lane >> 4, cl = lane & 15;
  const short* pa0 = &sA[(wm * 32 + cl) * LDA];
  const short* pa1 = pa0 + 16 * LDA;
  const short* wb = Wbt + (size_t)(wn * 64 + cl) * KEFF;   // tn adds tn*16*KEFF

  f32x4 acc[2][4];
  f32x4 zz = {0.f, 0.f, 0.f, 0.f};
#pragma unroll
  for (int tm = 0; tm < 2; ++tm)
#pragma unroll
    for (int tn = 0; tn < 4; ++tn) acc[tm][tn] = zz;

#pragma unroll
  for (int kstep = 0; kstep < 12; ++kstep) {
    int o = kstep * 32 + g * 8;
    bf16x8 a0 = *(const bf16x8*)&pa0[o];
    bf16x8 a1 = *(const bf16x8*)&pa1[o];
    const short* wk = wb + o;
    bf16x8 b0 = *(const bf16x8*)(wk);
    bf16x8 b1 = *(const bf16x8*)(wk + 16 * KEFF);
    bf16x8 b2 = *(const bf16x8*)(wk + 32 * KEFF);
    bf16x8 b3 = *(const bf16x8*)(wk + 48 * KEFF);
    acc[0][0] = __builtin_amdgcn_mfma_f32_16x16x32_bf16(a0, b0, acc[0][0], 0, 0, 0);
    acc[0][1] = __builtin_amdgcn_mfma_f32_16x16x32_bf16(a0, b1, acc[0][1], 0, 0, 0);
    acc[0][2] = __builtin_amdgcn_mfma_f32_16x16x32_bf16(a0, b2, acc[0][2], 0, 0, 0);
    acc[0][3] = __builtin_amdgcn_mfma_f32_16x16x32_bf16(a0, b3, acc[0][3], 0, 0, 0);
    acc[1][0] = __builtin_amdgcn_mfma_f32_16x16x32_bf16(a1, b0, acc[1][0], 0, 0, 0);
    acc[1][1] = __builtin_amdgcn_mfma_f32_16x16x32_bf16(a1, b1, acc[1][1], 0, 0, 0);
    acc[1][2] = __builtin_amdgcn_mfma_f32_16x16x32_bf16(a1, b2, acc[1][2], 0, 0, 0);
    acc[1][3] = __builtin_amdgcn_mfma_f32_16x16x32_bf16(a1, b3, acc[1][3], 0, 0, 0);
  }
  // ---- epilogue: bias + relu + DENSE store (no atomics) ----
#pragma unroll
  for (int tm = 0; tm < 2; ++tm)
#pragma unroll
    for (int reg = 0; reg < 4; ++reg) {
      int edge = wm * 32 + tm * 16 + g * 4 + reg;   // C/D: row=(lane>>4)*4+reg, col=lane&15
      if (edge < ne) {
        int dc = sMeta[edge][2];
        int rl = sMeta[edge][3];
        float* mp = msgbuf + (size_t)(base + edge) * D_;
#pragma unroll
        for (int tn = 0; tn < 4; ++tn) {
          int n = wn * 64 + tn * 16 + cl;
          float bias = T3b[dc * D_ + n] + T4[rl * D_ + n];
          mp[n] = fmaxf(acc[tm][tn][reg] + bias, 0.f);
        }
      }
    }
}

// ---------------- node update (MFMA): h = (sum of msgs)@upd_W + upd_b + h ----------------
// CSR gather replaces atomic aggr: per node, sum incoming msg rows (avg 1), then MFMA.
__global__ __launch_bounds__(256, 4) void k_upd(
    const float* __restrict__ msgbuf, const int* __restrict__ off,
    const int* __restrict__ cnt, const int* __restrict__ csr,
    const short* __restrict__ Wbt,   // [128][128] bf16 n-major
    const float* __restrict__ upd_b, float* __restrict__ h) {
  int base = blockIdx.x * 64;
  int tid = threadIdx.x;
  __shared__ __align__(16) short sU[64 * LDU];
  {
    int i = tid >> 2, q = tid & 3;
    int node = base + i;
    int o0 = off[node];
    int cn = cnt[node];
    float a[32];
#pragma unroll
    for (int j = 0; j < 32; ++j) a[j] = 0.f;
    for (int p = 0; p < cn; ++p) {
      const float4* mp = (const float4*)(msgbuf + (size_t)csr[o0 + p] * D_ + q * 32);
#pragma unroll
      for (int j = 0; j < 8; ++j) {
        float4 m = mp[j];
        a[4*j] += m.x; a[4*j+1] += m.y; a[4*j+2] += m.z; a[4*j+3] += m.w;
      }
    }
    short* rowp = &sU[i * LDU];
#pragma unroll
    for (int j = 0; j < 4; ++j) {
      float4 x = make_float4(a[8*j], a[8*j+1], a[8*j+2], a[8*j+3]);
      float4 y = make_float4(a[8*j+4], a[8*j+5], a[8*j+6], a[8*j+7]);
      *(bf16x8*)&rowp[q * 32 + j * 8] = pack8(x, y);
    }
  }
  __syncthreads();
  int lane = tid & 63, wv = tid >> 6;
  int wm = wv >> 1, wn = wv & 1;
  int g = lane >> 4, cl = lane & 15;
  const short* pa0 = &sU[(wm * 32 + cl) * LDU];
  const short* pa1 = pa0 + 16 * LDU;
  const short* wb = Wbt + (size_t)(wn * 64 + cl) * D_;

  f32x4 acc[2][4];
  f32x4 zz = {0.f, 0.f, 0.f, 0.f};
#pragma unroll
  for (int tm = 0; tm < 2; ++tm)
#pragma unroll
    for (int tn = 0; tn < 4; ++tn) acc[tm][tn] = zz;

#pragma unroll
  for (int kstep = 0; kstep < 4; ++kstep) {
    int o = kstep * 32 + g * 8;
    bf16x8 a0 = *(const bf16x8*)&pa0[o];
    bf16x8 a1 = *(const bf16x8*)&pa1[o];
    const short* wk = wb + o;
    bf16x8 b0 = *(const bf16x8*)(wk);
    bf16x8 b1 = *(const bf16x8*)(wk + 16 * D_);
    bf16x8 b2 = *(const bf16x8*)(wk + 32 * D_);
    bf16x8 b3 = *(const bf16x8*)(wk + 48 * D_);
    acc[0][0] = __builtin_amdgcn_mfma_f32_16x16x32_bf16(a0, b0, acc[0][0], 0, 0, 0);
    acc[0][1] = __builtin_amdgcn_mfma_f32_16x16x32_bf16(a0, b1, acc[0][1], 0, 0, 0);
    acc[0][2] = __builtin_amdgcn_mfma_f32_16x16x32_bf16(a0, b2, acc[0][2], 0, 0, 0);
    acc[0][3] = __builtin_amdgcn_mfma_f32_16x16x32_bf16(a0, b3, acc[0][3], 0, 0, 0);
    acc[1][0] = __builtin_amdgcn_mfma_f32_16x16x32_bf16(a1, b0, acc[1][0], 0, 0, 0);
    acc[1][1] = __builtin_amdgcn_mfma_f32_16x16x32_bf16(a1, b1, acc[1][1], 0, 0, 0);
    acc[1][2] = __builtin_amdgcn_mfma_f32_16x16x32_bf16(a1, b2, acc[1][2], 0, 0, 0);
    acc[1][3] = __builtin_amdgcn_mfma_f32_16x16x32_bf16(a1, b3, acc[1][3], 0, 0, 0);
  }
#pragma unroll
  for (int tm = 0; tm < 2; ++tm)
#pragma unroll
    for (int reg = 0; reg < 4; ++reg) {
      int grow = base + wm * 32 + tm * 16 + g * 4 + reg;
#pragma unroll
      for (int tn = 0; tn < 4; ++tn) {
        int n = wn * 64 + tn * 16 + cl;
        size_t gi = (size_t)grow * D_ + n;
        h[gi] = acc[tm][tn][reg] + upd_b[n] + h[gi];
      }
    }
}

// ---------------- scores: one wave per node, full att_in dot ----------------
__global__ __launch_bounds__(256) void k_score(const float* __restrict__ h,
    const int* __restrict__ node_mask, const float* __restrict__ r_query,
    const float* __restrict__ att_W, const float* __restrict__ att_b,
    float* __restrict__ sSg) {
  int wv = threadIdx.x >> 6, lane = threadIdx.x & 63;
  int node = blockIdx.x * 4 + wv;              // [0, B*N)
  int b = node >> 13;                           // N = 2^13
  float s;
  if (node_mask[node] == 0) {
    s = -1e9f;
  } else {
    float2 hv = *(const float2*)&h[(size_t)node * D_ + lane * 2];
    float2 w0 = *(const float2*)&att_W[lane * 2];
    float2 w1 = *(const float2*)&att_W[D_ + lane * 2];
    float2 rq = *(const float2*)&r_query[b * D_ + lane * 2];
    float v = hv.x * w0.x + hv.y * w0.y + rq.x * w1.x + rq.y * w1.y;
#pragma unroll
    for (int off = 32; off > 0; off >>= 1) v += __shfl_xor(v, off);
    v += att_b[0];
    s = v > 0.f ? v : 0.01f * v;
  }
  if (lane == 0) sSg[node] = s;
}

// ---------------- per-batch: softmax stats + top-20 + outputs ----------------
__global__ __launch_bounds__(1024) void k_top(const float* __restrict__ sSg,
    const float* __restrict__ h, const int* __restrict__ node_mask,
    float* __restrict__ out) {
  int b = blockIdx.x;
  int tid = threadIdx.x, lane = tid & 63, wv = tid >> 6;   // 16 waves
  __shared__ float sS[N_];
  __shared__ float sRw[16];
  __shared__ float sSegV[16];
  __shared__ int sSegI[16];
  __shared__ float sTopV[M_];
  __shared__ int sTopI[M_];
  __shared__ float sMax, sSum;
  const float4* gp = (const float4*)&sSg[(size_t)b * N_];
#pragma unroll
  for (int r = 0; r < 2; ++r) {
    float4 x = gp[tid + r * 1024];
    *(float4*)&sS[(tid + r * 1024) * 4] = x;
  }
  __syncthreads();
  // block max
  float lm = -INFINITY;
  for (int n = tid; n < N_; n += 1024) lm = fmaxf(lm, sS[n]);
#pragma unroll
  for (int off = 32; off > 0; off >>= 1) lm = fmaxf(lm, __shfl_xor(lm, off));
  if (lane == 0) sRw[wv] = lm;
  __syncthreads();
  if (tid == 0) {
    float m = sRw[0];
    for (int i = 1; i < 16; ++i) m = fmaxf(m, sRw[i]);
    sMax = m;
  }
  __syncthreads();
  float mx = sMax;
  // softmax denom
  float ls = 0.f;
  for (int n = tid; n < N_; n += 1024) ls += expf(sS[n] - mx);
#pragma unroll
  for (int off = 32; off > 0; off >>= 1) ls += __shfl_xor(ls, off);
  if (lane == 0) sRw[wv] = ls;
  __syncthreads();
  if (tid == 0) {
    float s = 0.f;
    for (int i = 0; i < 16; ++i) s += sRw[i];
    sSum = s;
  }
  // per-wave segment argmax (segment = 512 nodes), ties -> lowest index
  {
    float bv = -INFINITY; int bi = 0;
    int s0 = wv * 512;
    for (int t2 = 0; t2 < 8; ++t2) {
      int n = s0 + lane + t2 * 64;
      float x = sS[n];
      if (x > bv) { bv = x; bi = n; }
    }
#pragma unroll
    for (int off = 32; off > 0; off >>= 1) {
      float vv = __shfl_xor(bv, off); int ii = __shfl_xor(bi, off);
      if (vv > bv || (vv == bv && ii < bi)) { bv = vv; bi = ii; }
    }
    if (lane == 0) { sSegV[wv] = bv; sSegI[wv] = bi; }
  }
  __syncthreads();
  // top-20: pick best segment, knock out, rescan only that segment
  for (int j = 0; j < M_; ++j) {
    if (wv == 0) {
      float bv = (lane < 16) ? sSegV[lane] : -INFINITY;
      int bi = (lane < 16) ? sSegI[lane] : 0x7fffffff;
#pragma unroll
      for (int off = 32; off > 0; off >>= 1) {
        float vv = __shfl_xor(bv, off); int ii = __shfl_xor(bi, off);
        if (vv > bv || (vv == bv && ii < bi)) { bv = vv; bi = ii; }
      }
      if (lane == 0) { sTopV[j] = bv; sTopI[j] = bi; sS[bi] = -INFINITY; }
    }
    __syncthreads();
    int seg = sTopI[j] >> 9;
    if (wv == seg) {
      float bv = -INFINITY; int bi = 0;
      int s0 = wv * 512;
      for (int t2 = 0; t2 < 8; ++t2) {
        int n = s0 + lane + t2 * 64;
        float x = sS[n];
        if (x > bv) { bv = x; bi = n; }
      }
#pragma unroll
      for (int off = 32; off > 0; off >>= 1) {
        float vv = __shfl_xor(bv, off); int ii = __shfl_xor(bi, off);
        if (vv > bv || (vv == bv && ii < bi)) { bv = vv; bi = ii; }
      }
      if (lane == 0) { sSegV[wv] = bv; sSegI[wv] = bi; }
    }
    __syncthreads();
  }
  float sum = sSum;
  // t_state = (h*mask)[b,0,:]
  if (tid < D_) {
    float vv = node_mask[b * N_] ? h[(size_t)b * N_ * D_ + tid] : 0.f;
    out[B_ * M_ * D_ + b * D_ + tid] = vv;
  }
  // H_evd[b,j,:] = (h*mask)[b,idx_j,:] * alpha_j
  for (int s2 = tid; s2 < M_ * D_; s2 += 1024) {
    int j = s2 >> 7, d = s2 & 127;
    int idx = sTopI[j];
    float alpha = expf(sTopV[j] - mx) / sum;
    float hv = h[((size_t)b * N_ + idx) * D_ + d];
    if (!node_mask[b * N_ + idx]) hv = 0.f;
    out[(b * M_ + j) * D_ + d] = hv * alpha;
  }
}

// ---------------- host ----------------
extern "C" void kernel_launch(void* const* d_in, const int* in_sizes, int n_in,
                              void* d_out, int out_size, void* d_ws, size_t ws_size,
                              hipStream_t stream) {
  const int*   dists      = (const int*)d_in[0];
  const int*   edge_index = (const int*)d_in[1];
  const int*   rels       = (const int*)d_in[2];
  const int*   node_mask  = (const int*)d_in[3];
  const int*   edge_mask  = (const int*)d_in[4];
  const float* r_query    = (const float*)d_in[5];
  const float* conf       = (const float*)d_in[6];
  const float* noise      = (const float*)d_in[7];
  const float* dist_table = (const float*)d_in[8];
  const float* rel_table  = (const float*)d_in[9];
  const float* msg_W      = (const float*)d_in[10];
  const float* msg_b      = (const float*)d_in[11];
  const float* upd_W      = (const float*)d_in[12];
  const float* upd_b      = (const float*)d_in[13];
  const float* att_W      = (const float*)d_in[14];
  const float* att_b      = (const float*)d_in[15];
  float* out = (float*)d_out;

  char* ws = (char*)d_ws;
  size_t off0 = 0;
  auto alloc = [&](size_t bytes) {
    void* p = ws + off0;
    off0 = (off0 + bytes + 255) & ~(size_t)255;
    return p;
  };
  int*   count   = (int*)alloc(4);
  int*   list    = (int*)alloc((size_t)B_ * E_ * 4);
  float* h       = (float*)alloc((size_t)B_ * N_ * D_ * 4);
  float* msgbuf  = (float*)alloc((size_t)B_ * E_ * D_ * 4);
  int*   cnt     = (int*)alloc((size_t)B_ * N_ * 4);
  int*   offar   = (int*)alloc((size_t)B_ * N_ * 4);
  int*   cur     = (int*)alloc((size_t)B_ * N_ * 4);
  int*   csr     = (int*)alloc((size_t)B_ * E_ * 4);
  int*   bsum    = (int*)alloc(256 * 4);
  int*   boff    = (int*)alloc(256 * 4);
  short* Wbt_msg = (short*)alloc((size_t)L_ * D_ * KEFF * 2);
  short* Wbt_upd = (short*)alloc((size_t)L_ * D_ * D_ * 2);
  float* T3b     = (float*)alloc((size_t)L_ * 10 * D_ * 4);
  float* T4      = (float*)alloc((size_t)L_ * R_ * D_ * 4);
  float* scores  = (float*)alloc((size_t)B_ * N_ * 4);
  (void)ws_size; (void)in_sizes; (void)n_in; (void)out_size;

  hipMemsetAsync(count, 0, 4, stream);
  hipMemsetAsync(cnt, 0, (size_t)B_ * N_ * 4, stream);

  k_init_h<<<B_ * N_ * D_ / 4 / 256, 256, 0, stream>>>(dists, noise, dist_table, h);
  k_compact<<<B_ * E_ / 256, 256, 0, stream>>>(edge_mask, edge_index, count, list, cnt);
  k_scanA<<<256, 256, 0, stream>>>(cnt, bsum);
  k_scanB<<<1, 256, 0, stream>>>(bsum, boff);
  k_scanC<<<256, 256, 0, stream>>>(cnt, boff, offar, cur);
  k_fill<<<B_ * E_ / 256, 256, 0, stream>>>(count, list, edge_index, cur, csr);
  k_tables<<<L_ * 210, 128, 0, stream>>>(dist_table, rel_table, msg_W, msg_b, T3b, T4);
  k_wbt_msg<<<L_ * D_ * KEFF / 256, 256, 0, stream>>>(msg_W, Wbt_msg);
  k_wbt_upd<<<L_ * D_ * D_ / 256, 256, 0, stream>>>(upd_W, Wbt_upd);

  for (int k = 0; k < L_; ++k) {
    k_msg<<<B_ * E_ / 64, 256, 0, stream>>>(count, list, edge_index, rels, dists, h,
        rel_table, conf, Wbt_msg + (size_t)k * D_ * KEFF,
        T3b + k * 10 * D_, T4 + k * R_ * D_, msgbuf);
    k_upd<<<B_ * N_ / 64, 256, 0, stream>>>(msgbuf, offar, cnt, csr,
        Wbt_upd + (size_t)k * D_ * D_, upd_b + k * D_, h);
  }
  k_score<<<B_ * N_ / 4, 256, 0, stream>>>(h, node_mask, r_query, att_W, att_b, scores);
  k_top<<<B_, 1024, 0, stream>>>(scores, h, node_mask, out);
}